// Round 11
// baseline (754.420 us; speedup 1.0000x reference)
//
#include <hip/hip_runtime.h>

// VQ nearest-neighbor, two-pass, swapped-operand MFMA (round 11).
//  pass1: mfma(A=codebook_h, B=z_h): lane holds candidates for its own z-row in
//         acc regs; csq baked into a 33rd k-tile; in-lane TOP-3 fold;
//         codebook L2-resident per XCD (split-major mapping); A loaded in-body
//         (L2 hit); z staged via 3x16KB LDS rotation, counted vmcnt.
//  gather: certify winner / exact-rescore pool (bucket top-2 pairs) / flag row
//          only if some bucket's 3rd-best is within margin (~1-2%).
//  rescue: exact fp32 re-scan of flagged rows.
// score(k) = csq[k] - 2*z.c_k = -2*acc  (argmin score == argmax acc)

constexpr int Bn = 8192;
constexpr int Kn = 8192;
constexpr int Dn = 512;

using half8  = __attribute__((ext_vector_type(8)))  _Float16;
using f32x16 = __attribute__((ext_vector_type(16))) float;

// workspace layout (bytes), ~30.7MB
#define WS_CSQ  0u
#define WS_ZSQ  (32u*1024u)
#define WS_MAX  (64u*1024u)
#define WS_CNT  (64u*1024u + 64u)
#define WS_WL   (96u*1024u)
#define WS_P1   (1u*1024u*1024u)   // float4 [8192][64] (s1,i1,s2,i2) = 8MB
#define WS_P3   (9u*1024u*1024u)   // float2 [8192][64] (s3,0) = 4MB
#define WS_P2R  WS_P1              // rescue p2 aliases P1 (dead after gather)
#define WS_CIMG (13u*1024u*1024u)  // codebook h image: 64 blk x 33 kt x 4KB
#define WS_ZIMG (22u*1024u*1024u)  // z h image:        32 blk x 33 kt x 8KB

typedef __attribute__((address_space(3))) void       as3_void;
typedef const __attribute__((address_space(1))) void as1_cvoid;

#define MFMA16 __builtin_amdgcn_mfma_f32_32x32x16_f16

// Fragment-contiguous images: tile = blk*33 + kt; 1KB frag per 32-row group;
// chunk16B[kh*32+rr] = row grp*32+rr, k-half kh. kt=32 is the extension tile:
// codebook rows carry {-csq/2 hi, lo, 0..}, z rows carry {1,1,0..}.

// ---------------- prep_sums: row sumsq (exact fp32) + cmax -------------------
__global__ __launch_bounds__(256) void prep_sums(const float* __restrict__ Z,
                                                 const float* __restrict__ Cb,
                                                 char* __restrict__ ws) {
  const int w = threadIdx.x >> 6, lane = threadIdx.x & 63;
  const int rid = blockIdx.x * 4 + w;  // 0..16383
  if (blockIdx.x == 0 && threadIdx.x == 0) *(int*)(ws + WS_CNT) = 0;
  const bool isZ = rid < Bn;
  const int r = isZ ? rid : rid - Bn;
  const float* src = (isZ ? Z : Cb) + (size_t)r * Dn + lane * 8;
  const float4 v0 = *reinterpret_cast<const float4*>(src);
  const float4 v1 = *reinterpret_cast<const float4*>(src + 4);
  float ss = v0.x * v0.x + v0.y * v0.y + v0.z * v0.z + v0.w * v0.w +
             v1.x * v1.x + v1.y * v1.y + v1.z * v1.z + v1.w * v1.w;
#pragma unroll
  for (int off = 32; off; off >>= 1) ss += __shfl_xor(ss, off);
  if (lane == 0) {
    if (isZ) ((float*)(ws + WS_ZSQ))[r] = ss;
    else {
      ((float*)(ws + WS_CSQ))[r] = ss;
      atomicMax((int*)(ws + WS_MAX), __float_as_int(ss));  // ss>0: int order == float order
    }
  }
}

// ---------------- prep_img: wave-per-fragment, coalesced writes --------------
__global__ __launch_bounds__(256) void prep_img(const float* __restrict__ Z,
                                                const float* __restrict__ Cb,
                                                char* __restrict__ ws) {
  const int w = threadIdx.x >> 6, lane = threadIdx.x & 63;
  const int wid = blockIdx.x * 4 + w;  // 0..2559
  char* CI = ws + WS_CIMG;
  char* ZI = ws + WS_ZIMG;
  if (wid < 2048) {
    const bool isC = wid < 1024;
    const int f = isC ? wid : wid - 1024;
    const int koct = f & 3;
    const int grp = isC ? ((f >> 2) & 3) : ((f >> 2) & 7);
    const int blk = isC ? (f >> 4) : (f >> 5);
    const int rowbase = (isC ? blk * 128 : blk * 256) + grp * 32;
    const float* src = isC ? Cb : Z;
    char* img = isC ? CI : ZI;
    const int fr = isC ? 256 : 512;
    const int ktsel = lane & 1, rr = lane >> 1;
    const float* rowp = src + (size_t)(rowbase + rr) * Dn;
#pragma unroll
    for (int kp = 0; kp < 4; ++kp) {
      const int kt = koct * 8 + kp * 2 + ktsel;
      const float4 v0 = *reinterpret_cast<const float4*>(rowp + kt * 16);
      const float4 v1 = *reinterpret_cast<const float4*>(rowp + kt * 16 + 4);
      const float4 v2 = *reinterpret_cast<const float4*>(rowp + kt * 16 + 8);
      const float4 v3 = *reinterpret_cast<const float4*>(rowp + kt * 16 + 12);
      const float fl[16] = {v0.x, v0.y, v0.z, v0.w, v1.x, v1.y, v1.z, v1.w,
                            v2.x, v2.y, v2.z, v2.w, v3.x, v3.y, v3.z, v3.w};
      _Float16 h[16];
#pragma unroll
      for (int j = 0; j < 16; ++j) h[j] = (_Float16)fl[j];
      const half8 lo8 = {h[0], h[1], h[2], h[3], h[4], h[5], h[6], h[7]};
      const half8 hi8 = {h[8], h[9], h[10], h[11], h[12], h[13], h[14], h[15]};
      char* fb = img + ((size_t)(blk * 33 + kt) * fr + grp * 64) * 16;
      *reinterpret_cast<half8*>(fb + rr * 16) = lo8;        // kh=0 chunk
      *reinterpret_cast<half8*>(fb + 512 + rr * 16) = hi8;  // kh=1 chunk
    }
  } else if (wid < 2304) {  // C ext frags (csq baked): (blk 0..63, grp 0..3)
    const int e = wid - 2048;
    const int grp = e & 3, blk = e >> 2;
    half8 ev = {};
    if (lane < 32) {
      const float ss = ((const float*)(ws + WS_CSQ))[blk * 128 + grp * 32 + lane];
      const _Float16 hi = (_Float16)(-0.5f * ss);
      ev[0] = hi;
      ev[1] = (_Float16)(-0.5f * ss - (float)hi);
    }
    char* fb = CI + ((size_t)(blk * 33 + 32) * 256 + grp * 64) * 16;
    *reinterpret_cast<half8*>(fb + lane * 16) = ev;
  } else {  // Z ext frags ({1,1}): (blk 0..31, grp 0..7)
    const int e = wid - 2304;
    const int grp = e & 7, blk = e >> 3;
    half8 ev = {};
    if (lane < 32) { ev[0] = (_Float16)1.f; ev[1] = (_Float16)1.f; }
    char* fb = ZI + ((size_t)(blk * 33 + 32) * 512 + grp * 64) * 16;
    *reinterpret_cast<half8*>(fb + lane * 16) = ev;
  }
}

// ---------------- pass1 ------------------------------------------------------
// 512 blocks (2/CU), 256 thr (4 waves: wm = cb 64-half, wn = z 128-half).
// XCD mapping: xcd = bid&7 owns splits {2x, 2x+1} -> codebook slice ~1.06MB
// L2-RESIDENT; z streams from LLC through the staged (prefetch-2) path.
// Body u = 2 flat k-tiles (66 bodies, 4 panels x 33 kt); 3 x 16KB LDS rotation.
// A (codebook) loaded in-body (L2-hit); stage distance 2; vmcnt(4) ledger.
__global__ __launch_bounds__(256, 2) void vq_pass1(char* __restrict__ ws) {
  __shared__ uint4 lds4[3072];  // 48KB
  char* lds = (char*)lds4;
  const int t = threadIdx.x, lane = t & 63, w = t >> 6;
  const int wm = w >> 1, wn = w & 1;
  const int bid = blockIdx.x;
  const int zblk = bid >> 4;
  const int split = ((bid & 7) << 1) | ((bid >> 3) & 1);
  const int r31 = lane & 31, kh = lane >> 5;
  const char* CI = ws + WS_CIMG;
  const char* ZI = ws + WS_ZIMG;
  const size_t l16 = (size_t)lane * 16;
  const size_t zbase = (size_t)zblk * 33 * 8192 + (size_t)w * 2048 + l16;
  const size_t abase = (size_t)(wm * 2) * 1024 + l16;

  float qm1[4], qm2[4], qm3[4];
  int qi1[4], qi2[4];
#pragma unroll
  for (int nb = 0; nb < 4; ++nb) {
    qm1[nb] = -3e38f; qm2[nb] = -3e38f; qm3[nb] = -3e38f;
    qi1[nb] = 0x7fffffff; qi2[nb] = 0x7fffffff;
  }
  f32x16 acc[2][4] = {};

  auto STAGE = [&](int u, int bsel) {  // stage flat kts 2u,2u+1 (z side)
#pragma unroll
    for (int j = 0; j < 2; ++j) {
      const int f = 2 * u + j;
      const int k = f - (f / 33) * 33;
      const char* s = ZI + zbase + (size_t)k * 8192;
      char* d = lds + bsel * 16384 + j * 8192 + w * 2048;
      __builtin_amdgcn_global_load_lds((as1_cvoid*)(s), (as3_void*)(d), 16, 0, 0);
      __builtin_amdgcn_global_load_lds((as1_cvoid*)(s + 1024), (as3_void*)(d + 1024), 16, 0, 0);
    }
  };

  // prologue: stage bodies 0,1 -> buffers 0,1
  STAGE(0, 0);
  STAGE(1, 1);
  asm volatile("s_waitcnt vmcnt(0)" ::: "memory");
  __builtin_amdgcn_s_barrier();

  int cur = 0, stg = 2;
  for (int u = 0; u < 66; ++u) {
    // A for THIS body (codebook slice is L2-resident: ~250cyc, hides in-body)
    half8 a[4];
#pragma unroll
    for (int j = 0; j < 2; ++j) {
      const int f = 2 * u + j;
      const int p = f / 33, k = f - p * 33;
      const char* s = CI + (size_t)((split * 4 + p) * 33 + k) * 4096 + abase;
      a[j * 2 + 0] = *reinterpret_cast<const half8*>(s);
      a[j * 2 + 1] = *reinterpret_cast<const half8*>(s + 1024);
    }
    if (u + 2 < 66) STAGE(u + 2, stg);
#pragma unroll
    for (int j = 0; j < 2; ++j) {
      const char* bb = lds + cur * 16384 + j * 8192 + (size_t)wn * 4096 + l16;
      const half8 b0 = *reinterpret_cast<const half8*>(bb);
      const half8 b1 = *reinterpret_cast<const half8*>(bb + 1024);
      const half8 b2 = *reinterpret_cast<const half8*>(bb + 2048);
      const half8 b3 = *reinterpret_cast<const half8*>(bb + 3072);
      acc[0][0] = MFMA16(a[j * 2], b0, acc[0][0], 0, 0, 0);
      acc[0][1] = MFMA16(a[j * 2], b1, acc[0][1], 0, 0, 0);
      acc[0][2] = MFMA16(a[j * 2], b2, acc[0][2], 0, 0, 0);
      acc[0][3] = MFMA16(a[j * 2], b3, acc[0][3], 0, 0, 0);
      acc[1][0] = MFMA16(a[j * 2 + 1], b0, acc[1][0], 0, 0, 0);
      acc[1][1] = MFMA16(a[j * 2 + 1], b1, acc[1][1], 0, 0, 0);
      acc[1][2] = MFMA16(a[j * 2 + 1], b2, acc[1][2], 0, 0, 0);
      acc[1][3] = MFMA16(a[j * 2 + 1], b3, acc[1][3], 0, 0, 0);
      const int f = 2 * u + j;
      if (f - (f / 33) * 33 == 32) {
        // ---- in-lane top-3 fold over this panel's 128 candidates ----
        const int p = f / 33;
        const int cb = split * 512 + p * 128 + wm * 64 + 4 * kh;
#pragma unroll
        for (int nb = 0; nb < 4; ++nb) {
          float m1 = qm1[nb], m2 = qm2[nb], m3 = qm3[nb];
          int i1 = qi1[nb], i2 = qi2[nb];
#pragma unroll
          for (int ms = 0; ms < 2; ++ms)
#pragma unroll
            for (int r = 0; r < 16; ++r) {
              const float av = acc[ms][nb][r];
              const int ci = cb + ms * 32 + (r & 3) + 8 * (r >> 2);
              const bool g1 = (av > m1) || (av == m1 && ci < i1);
              const bool g2 = (av > m2) || (av == m2 && ci < i2);
              m3 = g2 ? m2 : fmaxf(m3, av);
              if (g1) { m2 = m1; i2 = i1; m1 = av; i1 = ci; }
              else if (g2) { m2 = av; i2 = ci; }
            }
          qm1[nb] = m1; qm2[nb] = m2; qm3[nb] = m3; qi1[nb] = i1; qi2[nb] = i2;
          acc[0][nb] = (f32x16)0.f;
          acc[1][nb] = (f32x16)0.f;
        }
      }
    }
    // ledger: S(u+1) must land; younger = S(u+2)[4] (A(u) already consumed)
    if (u < 63) asm volatile("s_waitcnt vmcnt(4)" ::: "memory");
    else        asm volatile("s_waitcnt vmcnt(0)" ::: "memory");
    __builtin_amdgcn_s_barrier();
    cur = cur == 2 ? 0 : cur + 1;
    stg = stg == 2 ? 0 : stg + 1;
  }

  // write per-bucket top-3 (score space: s = -2*m)
  float4* p1 = (float4*)(ws + WS_P1);
  float2* p3 = (float2*)(ws + WS_P3);
  const int bucket = split * 4 + wm * 2 + kh;
#pragma unroll
  for (int nb = 0; nb < 4; ++nb) {
    const int row = zblk * 256 + wn * 128 + nb * 32 + r31;
    p1[(size_t)row * 64 + bucket] =
        make_float4(-2.f * qm1[nb], (float)qi1[nb], -2.f * qm2[nb], (float)qi2[nb]);
    p3[(size_t)row * 64 + bucket] = make_float2(-2.f * qm3[nb], 0.f);
  }
}

// ---------------- gather: certify / exact-rescore pool / flag ----------------
__global__ __launch_bounds__(256) void gather_finalize(const float* __restrict__ Z,
                                                       const float* __restrict__ Cb,
                                                       char* __restrict__ ws,
                                                       float* __restrict__ zq,
                                                       float* __restrict__ idx_out) {
  const int w = threadIdx.x >> 6, l = threadIdx.x & 63;
  const int row = blockIdx.x * 4 + w;
  const float4 q = ((const float4*)(ws + WS_P1))[(size_t)row * 64 + l];
  const float s3 = ((const float2*)(ws + WS_P3))[(size_t)row * 64 + l].x;
  float s1 = q.x;
  int i1 = (int)q.y;
#pragma unroll
  for (int off = 1; off <= 32; off <<= 1) {
    const float os = __shfl_xor(s1, off); const int oi = __shfl_xor(i1, off);
    if (os < s1 || (os == s1 && oi < i1)) { s1 = os; i1 = oi; }
  }
  const float zs = ((const float*)(ws + WS_ZSQ))[row];
  const float cmax = __int_as_float(*(const int*)(ws + WS_MAX));
  // 2*eps bound: 2*(2^-10*||z||*||c||max + accum slack)
  const float thr = s1 + 4.0e-3f * sqrtf(zs * cmax) + 0.10f;
  int cnt = (q.x <= thr ? 1 : 0) + (q.z <= thr ? 1 : 0);
  int hide = (s3 <= thr) ? 1 : 0;
#pragma unroll
  for (int off = 1; off <= 32; off <<= 1) {
    cnt += __shfl_xor(cnt, off);
    hide |= __shfl_xor(hide, off);
  }
  if (cnt > 8 || hide) {
    if (l == 0) {
      const int pos = atomicAdd((int*)(ws + WS_CNT), 1);
      if (pos < Bn) ((int*)(ws + WS_WL))[pos] = row;
    }
    return;  // rescue writes this row
  }
  int winner = i1;
  if (cnt > 1) {  // exact fp32 rescore of the full visible pool (<=8)
    const float* csq = (const float*)(ws + WS_CSQ);
    const float4 z0 = *reinterpret_cast<const float4*>(Z + (size_t)row * Dn + l * 8);
    const float4 z1 = *reinterpret_cast<const float4*>(Z + (size_t)row * Dn + l * 8 + 4);
    float pa_s = (q.x <= thr) ? q.x : 3e38f;
    float pb_s = (q.z <= thr) ? q.z : 3e38f;
    const int pa_i = (int)q.y, pb_i = (int)q.w;
    float best_s = 3e38f;
    int best_i = 0x7fffffff;
    for (int it = 0; it < 8; ++it) {
      float cs_; int ci_;
      if (pb_s < pa_s || (pb_s == pa_s && pb_i < pa_i)) { cs_ = pb_s; ci_ = pb_i; }
      else { cs_ = pa_s; ci_ = pa_i; }
#pragma unroll
      for (int off = 1; off <= 32; off <<= 1) {
        const float os = __shfl_xor(cs_, off); const int oi = __shfl_xor(ci_, off);
        if (os < cs_ || (os == cs_ && oi < ci_)) { cs_ = os; ci_ = oi; }
      }
      if (cs_ > thr) break;  // wave-uniform
      if (ci_ == pa_i) pa_s = 3e38f;
      if (ci_ == pb_i) pb_s = 3e38f;
      const float4 c0 = *reinterpret_cast<const float4*>(Cb + (size_t)ci_ * Dn + l * 8);
      const float4 c1 = *reinterpret_cast<const float4*>(Cb + (size_t)ci_ * Dn + l * 8 + 4);
      float pa = z0.x * c0.x + z0.y * c0.y + z0.z * c0.z + z0.w * c0.w +
                 z1.x * c1.x + z1.y * c1.y + z1.z * c1.z + z1.w * c1.w;
#pragma unroll
      for (int off = 1; off <= 32; off <<= 1) pa += __shfl_xor(pa, off);
      const float se = csq[ci_] - 2.f * pa;
      if (se < best_s || (se == best_s && ci_ < best_i)) { best_s = se; best_i = ci_; }
    }
    winner = best_i;
  }
  const float4 o0 = *reinterpret_cast<const float4*>(Cb + (size_t)winner * Dn + l * 8);
  const float4 o1 = *reinterpret_cast<const float4*>(Cb + (size_t)winner * Dn + l * 8 + 4);
  *reinterpret_cast<float4*>(zq + (size_t)row * Dn + l * 8) = o0;
  *reinterpret_cast<float4*>(zq + (size_t)row * Dn + l * 8 + 4) = o1;
  if (l == 0) idx_out[row] = (float)winner;
}

// ---------------- rescue1: exact fp32 scores for flagged rows ----------------
__global__ __launch_bounds__(256) void rescue1(const float* __restrict__ Z,
                                               const float* __restrict__ Cb,
                                               char* __restrict__ ws) {
  const int cntRaw = *(const int*)(ws + WS_CNT);
  const int cnt = cntRaw > Bn ? Bn : cntRaw;
  if (cnt == 0) return;
  const int tiles_r = (cnt + 63) >> 6;
  const int total = tiles_r * 128;
  const int* wl = (const int*)(ws + WS_WL);
  const float* csq = (const float*)(ws + WS_CSQ);
  float2* p2 = (float2*)(ws + WS_P2R);
  __shared__ float As[32][68];
  __shared__ float Bs[32][68];
  __shared__ int wlrows[64];
  const int t = threadIdx.x;
  const int tx = t & 15, ty = t >> 4;
  const int sr = t >> 3, sc = (t & 7) * 4;
  for (int tile = blockIdx.x; tile < total; tile += gridDim.x) {
    const int tr = tile >> 7, tc = tile & 127;
    __syncthreads();
    if (t < 64) {
      const int wi = tr * 64 + t;
      wlrows[t] = wl[wi < cnt ? wi : cnt - 1];
    }
    __syncthreads();
    float acc[4][4] = {};
    for (int k0 = 0; k0 < Dn; k0 += 32) {
#pragma unroll
      for (int rr = 0; rr < 2; ++rr) {
        const int m = sr + rr * 32;
        const float4 v = *reinterpret_cast<const float4*>(Z + (size_t)wlrows[m] * Dn + k0 + sc);
        As[sc + 0][m] = v.x; As[sc + 1][m] = v.y; As[sc + 2][m] = v.z; As[sc + 3][m] = v.w;
        const float4 u = *reinterpret_cast<const float4*>(Cb + (size_t)(tc * 64 + m) * Dn + k0 + sc);
        Bs[sc + 0][m] = u.x; Bs[sc + 1][m] = u.y; Bs[sc + 2][m] = u.z; Bs[sc + 3][m] = u.w;
      }
      __syncthreads();
#pragma unroll
      for (int k = 0; k < 32; ++k) {
        const float4 a = *reinterpret_cast<const float4*>(&As[k][ty * 4]);
        const float4 b = *reinterpret_cast<const float4*>(&Bs[k][tx * 4]);
        acc[0][0] += a.x * b.x; acc[0][1] += a.x * b.y; acc[0][2] += a.x * b.z; acc[0][3] += a.x * b.w;
        acc[1][0] += a.y * b.x; acc[1][1] += a.y * b.y; acc[1][2] += a.y * b.z; acc[1][3] += a.y * b.w;
        acc[2][0] += a.z * b.x; acc[2][1] += a.z * b.y; acc[2][2] += a.z * b.z; acc[2][3] += a.z * b.w;
        acc[3][0] += a.w * b.x; acc[3][1] += a.w * b.y; acc[3][2] += a.w * b.z; acc[3][3] += a.w * b.w;
      }
      __syncthreads();
    }
#pragma unroll
    for (int i = 0; i < 4; ++i) {
      float bsv = 3e38f;
      int bi = 0;
#pragma unroll
      for (int j = 0; j < 4; ++j) {
        const int n = tc * 64 + tx * 4 + j;
        const float s = csq[n] - 2.f * acc[i][j];
        if (s < bsv || (s == bsv && n < bi)) { bsv = s; bi = n; }
      }
#pragma unroll
      for (int off = 1; off <= 8; off <<= 1) {
        const float os = __shfl_xor(bsv, off); const int oi = __shfl_xor(bi, off);
        if (os < bsv || (os == bsv && oi < bi)) { bsv = os; bi = oi; }
      }
      if (tx == 0) p2[(size_t)(tr * 64 + ty * 4 + i) * 128 + tc] = make_float2(bsv, (float)bi);
    }
  }
}

// ---------------- rescue2: combine col-tile minima + write -------------------
__global__ __launch_bounds__(64) void rescue2(const float* __restrict__ Cb,
                                              char* __restrict__ ws,
                                              float* __restrict__ zq,
                                              float* __restrict__ idx_out) {
  const int cntRaw = *(const int*)(ws + WS_CNT);
  const int cnt = cntRaw > Bn ? Bn : cntRaw;
  const int* wl = (const int*)(ws + WS_WL);
  const float2* p2 = (const float2*)(ws + WS_P2R);
  const int l = threadIdx.x;
  for (int rr = blockIdx.x; rr < cnt; rr += gridDim.x) {
    const int row = wl[rr];
    const float2 e1 = p2[(size_t)rr * 128 + l];
    const float2 e2 = p2[(size_t)rr * 128 + 64 + l];
    float bs_ = e1.x;
    int bi_ = (int)e1.y;
    if (e2.x < bs_ || (e2.x == bs_ && (int)e2.y < bi_)) { bs_ = e2.x; bi_ = (int)e2.y; }
#pragma unroll
    for (int off = 1; off <= 32; off <<= 1) {
      const float os = __shfl_xor(bs_, off); const int oi = __shfl_xor(bi_, off);
      if (os < bs_ || (os == bs_ && oi < bi_)) { bs_ = os; bi_ = oi; }
    }
    const float4 c0 = *reinterpret_cast<const float4*>(Cb + (size_t)bi_ * Dn + l * 8);
    const float4 c1 = *reinterpret_cast<const float4*>(Cb + (size_t)bi_ * Dn + l * 8 + 4);
    *reinterpret_cast<float4*>(zq + (size_t)row * Dn + l * 8) = c0;
    *reinterpret_cast<float4*>(zq + (size_t)row * Dn + l * 8 + 4) = c1;
    if (l == 0) idx_out[row] = (float)bi_;
  }
}

extern "C" void kernel_launch(void* const* d_in, const int* in_sizes, int n_in,
                              void* d_out, int out_size, void* d_ws, size_t ws_size,
                              hipStream_t stream) {
  const float* Z = (const float*)d_in[0];  // [B, D]
  const float* C = (const float*)d_in[1];  // [K, D]
  float* out = (float*)d_out;              // [B*D] z_q then [B] indices
  char* ws = (char*)d_ws;                  // ~30.7MB

  prep_sums<<<4096, 256, 0, stream>>>(Z, C, ws);
  prep_img<<<640, 256, 0, stream>>>(Z, C, ws);
  vq_pass1<<<512, 256, 0, stream>>>(ws);
  gather_finalize<<<2048, 256, 0, stream>>>(Z, C, ws, out, out + (size_t)Bn * Dn);
  rescue1<<<512, 256, 0, stream>>>(Z, C, ws);
  rescue2<<<256, 64, 0, stream>>>(C, ws, out, out + (size_t)Bn * Dn);
}

// Round 12
// 268.186 us; speedup vs baseline: 2.8130x; 2.8130x over previous
//
#include <hip/hip_runtime.h>

// VQ nearest-neighbor, two-pass, swapped-operand MFMA (round 12).
// pass1 = round-7 proven shape VERBATIM (register-exact: 128 VGPR + 128 AGPR,
// no spill) with ONE zero-register change: XCD mapping gives each XCD 2 splits
// -> codebook slice 1.06MB L2-RESIDENT (A-reg loads become L2 hits).
// gather margin tightened to the derived error bound (2.1e-3 vs 4e-3).
// score(k) = csq[k] - 2*z.c_k = -2*acc  (argmin score == argmax acc)

constexpr int Bn = 8192;
constexpr int Kn = 8192;
constexpr int Dn = 512;

using half8  = __attribute__((ext_vector_type(8)))  _Float16;
using f32x16 = __attribute__((ext_vector_type(16))) float;

// workspace layout (bytes), ~30.7MB
#define WS_CSQ  0u
#define WS_ZSQ  (32u*1024u)
#define WS_MAX  (64u*1024u)
#define WS_CNT  (64u*1024u + 64u)
#define WS_WL   (96u*1024u)
#define WS_P1   (1u*1024u*1024u)   // float4 [8192][64] (s1,i1,s2,0) = 8MB
#define WS_P2R  WS_P1              // rescue p2 aliases P1 (dead after gather)
#define WS_CIMG (13u*1024u*1024u)  // codebook h image: 64 blk x 33 kt x 4KB
#define WS_ZIMG (22u*1024u*1024u)  // z h image:        32 blk x 33 kt x 8KB

typedef __attribute__((address_space(3))) void       as3_void;
typedef const __attribute__((address_space(1))) void as1_cvoid;

#define MFMA16 __builtin_amdgcn_mfma_f32_32x32x16_f16

// Fragment-contiguous images: tile = blk*33 + kt; 1KB frag per 32-row group;
// chunk16B[kh*32+rr] = row grp*32+rr, k-half kh. kt=32 is the extension tile:
// codebook rows carry {-csq/2 hi, lo, 0..}, z rows carry {1,1,0..}.

// ---------------- prep_sums: row sumsq (exact fp32) + cmax -------------------
__global__ __launch_bounds__(256) void prep_sums(const float* __restrict__ Z,
                                                 const float* __restrict__ Cb,
                                                 char* __restrict__ ws) {
  const int w = threadIdx.x >> 6, lane = threadIdx.x & 63;
  const int rid = blockIdx.x * 4 + w;  // 0..16383
  if (blockIdx.x == 0 && threadIdx.x == 0) *(int*)(ws + WS_CNT) = 0;
  const bool isZ = rid < Bn;
  const int r = isZ ? rid : rid - Bn;
  const float* src = (isZ ? Z : Cb) + (size_t)r * Dn + lane * 8;
  const float4 v0 = *reinterpret_cast<const float4*>(src);
  const float4 v1 = *reinterpret_cast<const float4*>(src + 4);
  float ss = v0.x * v0.x + v0.y * v0.y + v0.z * v0.z + v0.w * v0.w +
             v1.x * v1.x + v1.y * v1.y + v1.z * v1.z + v1.w * v1.w;
#pragma unroll
  for (int off = 32; off; off >>= 1) ss += __shfl_xor(ss, off);
  if (lane == 0) {
    if (isZ) ((float*)(ws + WS_ZSQ))[r] = ss;
    else {
      ((float*)(ws + WS_CSQ))[r] = ss;
      atomicMax((int*)(ws + WS_MAX), __float_as_int(ss));  // ss>0: int order == float order
    }
  }
}

// ---------------- prep_img: wave-per-fragment, coalesced writes --------------
__global__ __launch_bounds__(256) void prep_img(const float* __restrict__ Z,
                                                const float* __restrict__ Cb,
                                                char* __restrict__ ws) {
  const int w = threadIdx.x >> 6, lane = threadIdx.x & 63;
  const int wid = blockIdx.x * 4 + w;  // 0..2559
  char* CI = ws + WS_CIMG;
  char* ZI = ws + WS_ZIMG;
  if (wid < 2048) {
    const bool isC = wid < 1024;
    const int f = isC ? wid : wid - 1024;
    const int koct = f & 3;
    const int grp = isC ? ((f >> 2) & 3) : ((f >> 2) & 7);
    const int blk = isC ? (f >> 4) : (f >> 5);
    const int rowbase = (isC ? blk * 128 : blk * 256) + grp * 32;
    const float* src = isC ? Cb : Z;
    char* img = isC ? CI : ZI;
    const int fr = isC ? 256 : 512;
    const int ktsel = lane & 1, rr = lane >> 1;
    const float* rowp = src + (size_t)(rowbase + rr) * Dn;
#pragma unroll
    for (int kp = 0; kp < 4; ++kp) {
      const int kt = koct * 8 + kp * 2 + ktsel;
      const float4 v0 = *reinterpret_cast<const float4*>(rowp + kt * 16);
      const float4 v1 = *reinterpret_cast<const float4*>(rowp + kt * 16 + 4);
      const float4 v2 = *reinterpret_cast<const float4*>(rowp + kt * 16 + 8);
      const float4 v3 = *reinterpret_cast<const float4*>(rowp + kt * 16 + 12);
      const float fl[16] = {v0.x, v0.y, v0.z, v0.w, v1.x, v1.y, v1.z, v1.w,
                            v2.x, v2.y, v2.z, v2.w, v3.x, v3.y, v3.z, v3.w};
      _Float16 h[16];
#pragma unroll
      for (int j = 0; j < 16; ++j) h[j] = (_Float16)fl[j];
      const half8 lo8 = {h[0], h[1], h[2], h[3], h[4], h[5], h[6], h[7]};
      const half8 hi8 = {h[8], h[9], h[10], h[11], h[12], h[13], h[14], h[15]};
      char* fb = img + ((size_t)(blk * 33 + kt) * fr + grp * 64) * 16;
      *reinterpret_cast<half8*>(fb + rr * 16) = lo8;        // kh=0 chunk
      *reinterpret_cast<half8*>(fb + 512 + rr * 16) = hi8;  // kh=1 chunk
    }
  } else if (wid < 2304) {  // C ext frags (csq baked): (blk 0..63, grp 0..3)
    const int e = wid - 2048;
    const int grp = e & 3, blk = e >> 2;
    half8 ev = {};
    if (lane < 32) {
      const float ss = ((const float*)(ws + WS_CSQ))[blk * 128 + grp * 32 + lane];
      const _Float16 hi = (_Float16)(-0.5f * ss);
      ev[0] = hi;
      ev[1] = (_Float16)(-0.5f * ss - (float)hi);
    }
    char* fb = CI + ((size_t)(blk * 33 + 32) * 256 + grp * 64) * 16;
    *reinterpret_cast<half8*>(fb + lane * 16) = ev;
  } else {  // Z ext frags ({1,1}): (blk 0..31, grp 0..7)
    const int e = wid - 2304;
    const int grp = e & 7, blk = e >> 3;
    half8 ev = {};
    if (lane < 32) { ev[0] = (_Float16)1.f; ev[1] = (_Float16)1.f; }
    char* fb = ZI + ((size_t)(blk * 33 + 32) * 512 + grp * 64) * 16;
    *reinterpret_cast<half8*>(fb + lane * 16) = ev;
  }
}

// ---------------- pass1: round-7 shape + L2-resident codebook mapping --------
// 512 blocks (2/CU), 256 thr (4 waves: wm=cb-half, wn=z-half).
// xcd = bid&7 owns splits {2x,2x+1} -> codebook 1.06MB L2-resident.
// z staged to LDS (3 rotating 16KB bufs, counted vmcnt); A global->reg dbuf.
__global__ __launch_bounds__(256, 2) void vq_pass1(char* __restrict__ ws) {
  __shared__ uint4 lds4[3072];  // 48KB
  char* lds = (char*)lds4;
  const int t = threadIdx.x, lane = t & 63, w = t >> 6;
  const int wm = w >> 1, wn = w & 1;
  const int bid = blockIdx.x;
  const int zblk = bid >> 4;
  const int split = ((bid & 7) << 1) | ((bid >> 3) & 1);
  const int r31 = lane & 31, kh = lane >> 5;
  const char* CI = ws + WS_CIMG;
  const char* ZI = ws + WS_ZIMG;
  const size_t l16 = (size_t)lane * 16;
  const size_t zsrc = (size_t)zblk * 33 * 8192 + (size_t)w * 2048 + l16;
  const size_t abase = (size_t)(wm * 2) * 1024 + l16;

  float qs1[4], qs2[4];
  int qi1[4];
#pragma unroll
  for (int nb = 0; nb < 4; ++nb) { qs1[nb] = -3e38f; qs2[nb] = -3e38f; qi1[nb] = 0x7fffffff; }

  f32x16 acc[2][4] = {};
  half8 aA0, aA1, aB0, aB1;

  auto STAGE = [&](int kv, int bsel) {  // z tile depends only on kt
    const char* s = ZI + zsrc + (size_t)kv * 8192;
    char* d = lds + bsel * 8192 + w * 2048;
    __builtin_amdgcn_global_load_lds((as1_cvoid*)(s), (as3_void*)(d), 16, 0, 0);
    __builtin_amdgcn_global_load_lds((as1_cvoid*)(s + 1024), (as3_void*)(d + 1024), 16, 0, 0);
  };

  // prologue
  STAGE(0, 0);
  STAGE(1, 1);
  {
    const char* s = CI + (size_t)(split * 4 * 33 + 0) * 4096 + abase;
    aA0 = *reinterpret_cast<const half8*>(s);
    aA1 = *reinterpret_cast<const half8*>(s + 1024);
  }
  asm volatile("s_waitcnt vmcnt(0)" ::: "memory");
  __builtin_amdgcn_s_barrier();

  int kt = 0, panel = 0, cur = 0, stg = 2;
#pragma unroll 2
  for (int u = 0; u < 132; ++u) {
    int k1 = kt + 1, p1 = panel;
    if (k1 == 33) { k1 = 0; ++p1; }
    int k2 = kt + 2;
    if (k2 >= 33) k2 -= 33;
    if (u + 1 < 132) {  // codebook frags for next step -> alternate reg set
      const char* s = CI + (size_t)((split * 4 + p1) * 33 + k1) * 4096 + abase;
      if ((u & 1) == 0) {
        aB0 = *reinterpret_cast<const half8*>(s);
        aB1 = *reinterpret_cast<const half8*>(s + 1024);
      } else {
        aA0 = *reinterpret_cast<const half8*>(s);
        aA1 = *reinterpret_cast<const half8*>(s + 1024);
      }
    }
    if (u + 2 < 132) STAGE(k2, stg);
    const char* bb = lds + cur * 8192 + (size_t)wn * 4096 + l16;
    const half8 b0 = *reinterpret_cast<const half8*>(bb);
    const half8 b1 = *reinterpret_cast<const half8*>(bb + 1024);
    const half8 b2 = *reinterpret_cast<const half8*>(bb + 2048);
    const half8 b3 = *reinterpret_cast<const half8*>(bb + 3072);
    const half8 a0 = (u & 1) ? aB0 : aA0;
    const half8 a1 = (u & 1) ? aB1 : aA1;
    acc[0][0] = MFMA16(a0, b0, acc[0][0], 0, 0, 0);
    acc[0][1] = MFMA16(a0, b1, acc[0][1], 0, 0, 0);
    acc[0][2] = MFMA16(a0, b2, acc[0][2], 0, 0, 0);
    acc[0][3] = MFMA16(a0, b3, acc[0][3], 0, 0, 0);
    acc[1][0] = MFMA16(a1, b0, acc[1][0], 0, 0, 0);
    acc[1][1] = MFMA16(a1, b1, acc[1][1], 0, 0, 0);
    acc[1][2] = MFMA16(a1, b2, acc[1][2], 0, 0, 0);
    acc[1][3] = MFMA16(a1, b3, acc[1][3], 0, 0, 0);
    if (kt == 32) {  // ---- in-lane fold: top-2 over this panel's candidates ----
      const int cbase = split * 512 + panel * 128 + wm * 64 + 4 * kh;
#pragma unroll
      for (int nb = 0; nb < 4; ++nb) {
        float m1 = qs1[nb], m2 = qs2[nb];
        int i1 = qi1[nb];
#pragma unroll
        for (int ms = 0; ms < 2; ++ms)
#pragma unroll
          for (int r = 0; r < 16; ++r) {
            const float a = acc[ms][nb][r];
            const int ci = cbase + ms * 32 + (r & 3) + 8 * (r >> 2);
            const bool gt = (a > m1) || (a == m1 && ci < i1);
            const float nm2 = gt ? m1 : fmaxf(m2, a);
            m1 = gt ? a : m1;
            i1 = gt ? ci : i1;
            m2 = nm2;
          }
        qs1[nb] = m1; qs2[nb] = m2; qi1[nb] = i1;
      }
#pragma unroll
      for (int ms = 0; ms < 2; ++ms)
#pragma unroll
        for (int nb = 0; nb < 4; ++nb) acc[ms][nb] = (f32x16)0.f;
    }
    if (u < 130) asm volatile("s_waitcnt vmcnt(4)" ::: "memory");
    else         asm volatile("s_waitcnt vmcnt(2)" ::: "memory");
    __builtin_amdgcn_s_barrier();
    ++kt;
    if (kt == 33) { kt = 0; ++panel; }
    cur = (cur == 2) ? 0 : cur + 1;
    stg = (stg == 2) ? 0 : stg + 1;
  }

  // write per-bucket top-2 (score space: s = -2*m)
  float4* part = (float4*)(ws + WS_P1);
  const int bucket = split * 4 + wm * 2 + kh;
#pragma unroll
  for (int nb = 0; nb < 4; ++nb) {
    const int row = zblk * 256 + wn * 128 + nb * 32 + r31;
    part[(size_t)row * 64 + bucket] =
        make_float4(-2.f * qs1[nb], (float)qi1[nb], -2.f * qs2[nb], 0.f);
  }
}

// ---------------- gather: certify / exact-rescore<=4 / flag ------------------
__global__ __launch_bounds__(256) void gather_finalize(const float* __restrict__ Z,
                                                       const float* __restrict__ Cb,
                                                       char* __restrict__ ws,
                                                       float* __restrict__ zq,
                                                       float* __restrict__ idx_out) {
  const int w = threadIdx.x >> 6, l = threadIdx.x & 63;
  const int row = blockIdx.x * 4 + w;
  const float4 q = ((const float4*)(ws + WS_P1))[(size_t)row * 64 + l];
  float s1 = q.x;
  int i1 = (int)q.y;
#pragma unroll
  for (int off = 1; off <= 32; off <<= 1) {
    const float os = __shfl_xor(s1, off); const int oi = __shfl_xor(i1, off);
    if (os < s1 || (os == s1 && oi < i1)) { s1 = os; i1 = oi; }
  }
  const float zs = ((const float*)(ws + WS_ZSQ))[row];
  const float cmax = __int_as_float(*(const int*)(ws + WS_MAX));
  // 2*eps: eps <= 2^-10*||z||*||c||max + fp32-accum slack
  const float thr = s1 + 2.1e-3f * sqrtf(zs * cmax) + 0.05f;
  int cnt = (q.x <= thr ? 1 : 0) + (q.z <= thr ? 1 : 0);
  int hide = (q.z <= thr) ? 1 : 0;
#pragma unroll
  for (int off = 1; off <= 32; off <<= 1) {
    cnt += __shfl_xor(cnt, off);
    hide |= __shfl_xor(hide, off);
  }
  if (cnt >= 5 || hide) {
    if (l == 0) {
      const int pos = atomicAdd((int*)(ws + WS_CNT), 1);
      if (pos < Bn) ((int*)(ws + WS_WL))[pos] = row;
    }
    return;  // rescue writes this row
  }
  int winner = i1;
  if (cnt > 1) {  // exact fp32 rescore of all visible candidates <= thr (<=4)
    const float* csq = (const float*)(ws + WS_CSQ);
    const float4 z0 = *reinterpret_cast<const float4*>(Z + (size_t)row * Dn + l * 8);
    const float4 z1 = *reinterpret_cast<const float4*>(Z + (size_t)row * Dn + l * 8 + 4);
    float mycand = (q.x <= thr) ? q.x : 3e38f;
    const int myid = (int)q.y;
    float best_s = 3e38f;
    int best_i = 0x7fffffff;
    for (int it = 0; it < 4; ++it) {
      float cs_ = mycand;
      int ci_ = myid;
#pragma unroll
      for (int off = 1; off <= 32; off <<= 1) {
        const float os = __shfl_xor(cs_, off); const int oi = __shfl_xor(ci_, off);
        if (os < cs_ || (os == cs_ && oi < ci_)) { cs_ = os; ci_ = oi; }
      }
      if (cs_ > thr) break;  // wave-uniform
      if (myid == ci_) mycand = 3e38f;
      const float4 c0 = *reinterpret_cast<const float4*>(Cb + (size_t)ci_ * Dn + l * 8);
      const float4 c1 = *reinterpret_cast<const float4*>(Cb + (size_t)ci_ * Dn + l * 8 + 4);
      float pa = z0.x * c0.x + z0.y * c0.y + z0.z * c0.z + z0.w * c0.w +
                 z1.x * c1.x + z1.y * c1.y + z1.z * c1.z + z1.w * c1.w;
#pragma unroll
      for (int off = 1; off <= 32; off <<= 1) pa += __shfl_xor(pa, off);
      const float se = csq[ci_] - 2.f * pa;
      if (se < best_s || (se == best_s && ci_ < best_i)) { best_s = se; best_i = ci_; }
    }
    winner = best_i;
  }
  const float4 o0 = *reinterpret_cast<const float4*>(Cb + (size_t)winner * Dn + l * 8);
  const float4 o1 = *reinterpret_cast<const float4*>(Cb + (size_t)winner * Dn + l * 8 + 4);
  *reinterpret_cast<float4*>(zq + (size_t)row * Dn + l * 8) = o0;
  *reinterpret_cast<float4*>(zq + (size_t)row * Dn + l * 8 + 4) = o1;
  if (l == 0) idx_out[row] = (float)winner;
}

// ---------------- rescue1: exact fp32 scores for flagged rows ----------------
__global__ __launch_bounds__(256) void rescue1(const float* __restrict__ Z,
                                               const float* __restrict__ Cb,
                                               char* __restrict__ ws) {
  const int cntRaw = *(const int*)(ws + WS_CNT);
  const int cnt = cntRaw > Bn ? Bn : cntRaw;
  if (cnt == 0) return;
  const int tiles_r = (cnt + 63) >> 6;
  const int total = tiles_r * 128;
  const int* wl = (const int*)(ws + WS_WL);
  const float* csq = (const float*)(ws + WS_CSQ);
  float2* p2 = (float2*)(ws + WS_P2R);
  __shared__ float As[32][68];
  __shared__ float Bs[32][68];
  __shared__ int wlrows[64];
  const int t = threadIdx.x;
  const int tx = t & 15, ty = t >> 4;
  const int sr = t >> 3, sc = (t & 7) * 4;
  for (int tile = blockIdx.x; tile < total; tile += gridDim.x) {
    const int tr = tile >> 7, tc = tile & 127;
    __syncthreads();
    if (t < 64) {
      const int wi = tr * 64 + t;
      wlrows[t] = wl[wi < cnt ? wi : cnt - 1];
    }
    __syncthreads();
    float acc[4][4] = {};
    for (int k0 = 0; k0 < Dn; k0 += 32) {
#pragma unroll
      for (int rr = 0; rr < 2; ++rr) {
        const int m = sr + rr * 32;
        const float4 v = *reinterpret_cast<const float4*>(Z + (size_t)wlrows[m] * Dn + k0 + sc);
        As[sc + 0][m] = v.x; As[sc + 1][m] = v.y; As[sc + 2][m] = v.z; As[sc + 3][m] = v.w;
        const float4 u = *reinterpret_cast<const float4*>(Cb + (size_t)(tc * 64 + m) * Dn + k0 + sc);
        Bs[sc + 0][m] = u.x; Bs[sc + 1][m] = u.y; Bs[sc + 2][m] = u.z; Bs[sc + 3][m] = u.w;
      }
      __syncthreads();
#pragma unroll
      for (int k = 0; k < 32; ++k) {
        const float4 a = *reinterpret_cast<const float4*>(&As[k][ty * 4]);
        const float4 b = *reinterpret_cast<const float4*>(&Bs[k][tx * 4]);
        acc[0][0] += a.x * b.x; acc[0][1] += a.x * b.y; acc[0][2] += a.x * b.z; acc[0][3] += a.x * b.w;
        acc[1][0] += a.y * b.x; acc[1][1] += a.y * b.y; acc[1][2] += a.y * b.z; acc[1][3] += a.y * b.w;
        acc[2][0] += a.z * b.x; acc[2][1] += a.z * b.y; acc[2][2] += a.z * b.z; acc[2][3] += a.z * b.w;
        acc[3][0] += a.w * b.x; acc[3][1] += a.w * b.y; acc[3][2] += a.w * b.z; acc[3][3] += a.w * b.w;
      }
      __syncthreads();
    }
#pragma unroll
    for (int i = 0; i < 4; ++i) {
      float bsv = 3e38f;
      int bi = 0;
#pragma unroll
      for (int j = 0; j < 4; ++j) {
        const int n = tc * 64 + tx * 4 + j;
        const float s = csq[n] - 2.f * acc[i][j];
        if (s < bsv || (s == bsv && n < bi)) { bsv = s; bi = n; }
      }
#pragma unroll
      for (int off = 1; off <= 8; off <<= 1) {
        const float os = __shfl_xor(bsv, off); const int oi = __shfl_xor(bi, off);
        if (os < bsv || (os == bsv && oi < bi)) { bsv = os; bi = oi; }
      }
      if (tx == 0) p2[(size_t)(tr * 64 + ty * 4 + i) * 128 + tc] = make_float2(bsv, (float)bi);
    }
  }
}

// ---------------- rescue2: combine col-tile minima + write -------------------
__global__ __launch_bounds__(64) void rescue2(const float* __restrict__ Cb,
                                              char* __restrict__ ws,
                                              float* __restrict__ zq,
                                              float* __restrict__ idx_out) {
  const int cntRaw = *(const int*)(ws + WS_CNT);
  const int cnt = cntRaw > Bn ? Bn : cntRaw;
  const int* wl = (const int*)(ws + WS_WL);
  const float2* p2 = (const float2*)(ws + WS_P2R);
  const int l = threadIdx.x;
  for (int rr = blockIdx.x; rr < cnt; rr += gridDim.x) {
    const int row = wl[rr];
    const float2 e1 = p2[(size_t)rr * 128 + l];
    const float2 e2 = p2[(size_t)rr * 128 + 64 + l];
    float bs_ = e1.x;
    int bi_ = (int)e1.y;
    if (e2.x < bs_ || (e2.x == bs_ && (int)e2.y < bi_)) { bs_ = e2.x; bi_ = (int)e2.y; }
#pragma unroll
    for (int off = 1; off <= 32; off <<= 1) {
      const float os = __shfl_xor(bs_, off); const int oi = __shfl_xor(bi_, off);
      if (os < bs_ || (os == bs_ && oi < bi_)) { bs_ = os; bi_ = oi; }
    }
    const float4 c0 = *reinterpret_cast<const float4*>(Cb + (size_t)bi_ * Dn + l * 8);
    const float4 c1 = *reinterpret_cast<const float4*>(Cb + (size_t)bi_ * Dn + l * 8 + 4);
    *reinterpret_cast<float4*>(zq + (size_t)row * Dn + l * 8) = c0;
    *reinterpret_cast<float4*>(zq + (size_t)row * Dn + l * 8 + 4) = c1;
    if (l == 0) idx_out[row] = (float)bi_;
  }
}

extern "C" void kernel_launch(void* const* d_in, const int* in_sizes, int n_in,
                              void* d_out, int out_size, void* d_ws, size_t ws_size,
                              hipStream_t stream) {
  const float* Z = (const float*)d_in[0];  // [B, D]
  const float* C = (const float*)d_in[1];  // [K, D]
  float* out = (float*)d_out;              // [B*D] z_q then [B] indices
  char* ws = (char*)d_ws;                  // ~30.7MB

  prep_sums<<<4096, 256, 0, stream>>>(Z, C, ws);
  prep_img<<<640, 256, 0, stream>>>(Z, C, ws);
  vq_pass1<<<512, 256, 0, stream>>>(ws);
  gather_finalize<<<2048, 256, 0, stream>>>(Z, C, ws, out, out + (size_t)Bn * Dn);
  rescue1<<<512, 256, 0, stream>>>(Z, C, ws);
  rescue2<<<256, 64, 0, stream>>>(C, ws, out, out + (size_t)Bn * Dn);
}